// Round 11
// baseline (131.143 us; speedup 1.0000x reference)
//
#include <hip/hip_runtime.h>
#include <hip/hip_bf16.h>

#define H_DIM 768
#define S_LEN 128
#define NT32 24  // 768 / 32 K-tiles

typedef __attribute__((ext_vector_type(8))) short short8;
typedef __attribute__((ext_vector_type(4))) float f32x4;

__device__ __forceinline__ void gload_lds16(const void* g, void* l) {
  __builtin_amdgcn_global_load_lds(
      (const __attribute__((address_space(1))) unsigned int*)g,
      (__attribute__((address_space(3))) unsigned int*)l, 16, 0, 0);
}

// ---------------- Kernel 1: per-token L2 normalize, fp32 -> bf16 (both tensors) ----------------
__global__ __launch_bounds__(256) void norm_bf16_kernel(
    const float* __restrict__ x1, const float* __restrict__ x2,
    unsigned short* __restrict__ xn1, unsigned short* __restrict__ xn2) {
  const int gid = blockIdx.x;
  const float* row;
  unsigned short* orow;
  if (gid < 8192) { row = x1 + (size_t)gid * H_DIM; orow = xn1 + (size_t)gid * H_DIM; }
  else            { row = x2 + (size_t)(gid - 8192) * H_DIM; orow = xn2 + (size_t)(gid - 8192) * H_DIM; }
  const int tid = threadIdx.x;
  float4 v = make_float4(0.f, 0.f, 0.f, 0.f);
  float ss = 0.f;
  if (tid < 192) {  // 192 * 4 = 768 floats
    v = reinterpret_cast<const float4*>(row)[tid];
    ss = v.x * v.x + v.y * v.y + v.z * v.z + v.w * v.w;
  }
#pragma unroll
  for (int o = 32; o > 0; o >>= 1) ss += __shfl_down(ss, o);
  __shared__ float ws[4];
  if ((tid & 63) == 0) ws[tid >> 6] = ss;
  __syncthreads();
  const float scale = 1.0f / sqrtf(ws[0] + ws[1] + ws[2] + ws[3]);
  if (tid < 192) {
    union { ushort4 u; __hip_bfloat16 h[4]; } o;
    o.h[0] = __float2bfloat16(v.x * scale);
    o.h[1] = __float2bfloat16(v.y * scale);
    o.h[2] = __float2bfloat16(v.z * scale);
    o.h[3] = __float2bfloat16(v.w * scale);
    reinterpret_cast<ushort4*>(orow)[tid] = o.u;
  }
}

// Stage one BK=32 K-tile (A 128x32 = 8 KB, B 256x32 = 16 KB) into the buffers
// at byte offsets ABOFF/BBOFF. 3 gload_lds/thread. Linear LDS dest,
// inverse-swizzled GLOBAL source chunk (rule 21; involution slot^((row>>1)&3)).
#define STAGE32(ABOFF, BBOFF, KT)                                         \
  {                                                                       \
    const int k0e = (KT) * 32;                                            \
    gload_lds16(A0 + a_src + k0e, smem + (ABOFF) + a_dst);                \
    gload_lds16(B0 + b_src0 + k0e, smem + (BBOFF) + b_dst0);              \
    gload_lds16(B0 + b_src1 + k0e, smem + (BBOFF) + b_dst1);              \
    __builtin_amdgcn_sched_barrier(0); /* keep DMA issue early */         \
  }

// Compute one BK=32 K-tile from the buffers at ABOFF/BBOFF: 8 ds_read_b128
// (base + immediate offsets; swizzle slot is lane-constant) + 16 MFMA.
#define COMPUTE32(ABOFF, BBOFF)                                           \
  {                                                                       \
    short8 av[4], bv[4];                                                  \
    _Pragma("unroll")                                                     \
    for (int i = 0; i < 4; ++i)                                           \
      av[i] = *reinterpret_cast<const short8*>(smem + (ABOFF) + aoff + i * 1024); \
    _Pragma("unroll")                                                     \
    for (int j = 0; j < 4; ++j)                                           \
      bv[j] = *reinterpret_cast<const short8*>(smem + (BBOFF) + boff + j * 1024); \
    __builtin_amdgcn_s_setprio(1);                                        \
    _Pragma("unroll")                                                     \
    for (int i = 0; i < 4; ++i)                                           \
      _Pragma("unroll")                                                   \
      for (int j = 0; j < 4; ++j)                                         \
        acc[i][j] = __builtin_amdgcn_mfma_f32_16x16x32_bf16(              \
            av[i], bv[j], acc[i][j], 0, 0, 0);                            \
    __builtin_amdgcn_s_setprio(0);                                        \
  }

// ---------------- Kernel 2: one block = pair-batch (a, {b0,b1}), 128x256 tile ----------------
// Round-10 tile/epilogue, with the K-loop rebuilt as the T3 minimum-2-phase
// pipeline at BK=32: both operands double-buffered (2x24 KB = 48 KB, same
// footprint as round 10 -> 2 blocks/CU kept), stage(t+1) issued BEFORE
// compute(t), vmcnt(0)+barrier AFTER compute — staging latency hides under
// the MFMA phase instead of being drained in front of it.
__global__ __launch_bounds__(512, 2) void rwmd_kernel(
    const unsigned short* __restrict__ xn1, const unsigned short* __restrict__ xn2,
    const int* __restrict__ mask1, const int* __restrict__ mask2,
    float* __restrict__ out) {
  // byte layout: A buf0 [0,8K) buf1 [8K,16K); B buf0 [16K,32K) buf1 [32K,48K)
  __shared__ __align__(16) unsigned char smem[49152];  // 48 KB exactly
  float* const rpart = (float*)smem;                   // overlay after K-loop: [4][128]
  float* const cpart = (float*)(smem + 2048);          // overlay: [2][256]

  const int a = blockIdx.x >> 5;   // 64 a's
  const int bp = blockIdx.x & 31;  // 32 b-pairs
  const int b0i = bp * 2;
  const int tid = threadIdx.x;
  const int lane = tid & 63;
  const int w = tid >> 6;
  const int wm = w >> 2, wn = w & 3;
  const int g = lane >> 4, rl = lane & 15;

  const unsigned short* A0 = xn1 + (size_t)a * (S_LEN * H_DIM);
  const unsigned short* B0 = xn2 + (size_t)b0i * (S_LEN * H_DIM);  // 256 rows

  // staging addresses (chunk = 16 B = 8 elems; 4 chunks per 32-elem row)
  const int ra = tid >> 2;                       // A row 0..127
  const int ca = (tid & 3) ^ ((ra >> 1) & 3);    // inverse-swizzled source chunk
  const size_t a_src = (size_t)ra * H_DIM + ca * 8;
  const int a_dst = tid * 16;                    // linear LDS bytes
  const int sb0 = tid, sb1 = 512 + tid;          // B chunks 0..1023
  const int rb0 = sb0 >> 2, rb1 = sb1 >> 2;      // B rows 0..255
  const int cb0 = (sb0 & 3) ^ ((rb0 >> 1) & 3);
  const int cb1 = (sb1 & 3) ^ ((rb1 >> 1) & 3);
  const size_t b_src0 = (size_t)rb0 * H_DIM + cb0 * 8;
  const size_t b_src1 = (size_t)rb1 * H_DIM + cb1 * 8;
  const int b_dst0 = sb0 * 16, b_dst1 = sb1 * 16;

  // read addresses: row r holds k-chunk g at slot g^((r>>1)&3); for
  // r = base + rl the swizzle term reduces to (rl>>1)&3 (lane-constant).
  const int slot = g ^ ((rl >> 1) & 3);
  const int aoff = (wm * 64 + rl) * 64 + slot * 16;  // + i*1024
  const int boff = (wn * 64 + rl) * 64 + slot * 16;  // + j*1024

  f32x4 acc[4][4];
#pragma unroll
  for (int i = 0; i < 4; ++i)
#pragma unroll
    for (int j = 0; j < 4; ++j) acc[i][j] = (f32x4){0.f, 0.f, 0.f, 0.f};

  // prologue: K-tile 0 into buf0
  STAGE32(0, 16384, 0);
  asm volatile("s_waitcnt vmcnt(0)" ::: "memory");
  __builtin_amdgcn_s_barrier();

#pragma unroll 1
  for (int t = 0; t < NT32; t += 2) {
    STAGE32(8192, 32768, t + 1);   // t+1 -> buf1 (t+1 <= 23 always)
    COMPUTE32(0, 16384);           // compute t from buf0
    asm volatile("s_waitcnt vmcnt(0)" ::: "memory");  // t+1 landed
    __builtin_amdgcn_s_barrier();  // all waves done reading buf0 + see buf1
    if (t + 2 < NT32) STAGE32(0, 16384, t + 2);       // t+2 -> buf0
    COMPUTE32(8192, 32768);        // compute t+1 from buf1
    asm volatile("s_waitcnt vmcnt(0)" ::: "memory");
    __builtin_amdgcn_s_barrier();
  }

  // ---- per-thread packed mask bits from global (L2-hot) ----
  __builtin_amdgcn_sched_barrier(0);
  unsigned mcol = 0, mrow = 0;
#pragma unroll
  for (int j = 0; j < 4; ++j)
    mcol |= (mask2[b0i * S_LEN + wn * 64 + j * 16 + rl] ? 1u : 0u) << j;
#pragma unroll
  for (int i = 0; i < 4; ++i)
#pragma unroll
    for (int r = 0; r < 4; ++r)
      mrow |= (mask1[a * S_LEN + wm * 64 + i * 16 + g * 4 + r] ? 1u : 0u) << (i * 4 + r);

  __syncthreads();  // staging LDS dead -> safe to overlay rpart/cpart

  // ---- in-register masked reductions ----
  // acc[i][j][r]: row = wm*64 + i*16 + g*4 + r, col = wn*64 + j*16 + rl
#pragma unroll
  for (int i = 0; i < 4; ++i) {
#pragma unroll
    for (int r = 0; r < 4; ++r) {
      float pm = -INFINITY;
#pragma unroll
      for (int j = 0; j < 4; ++j)
        pm = fmaxf(pm, ((mcol >> j) & 1) ? acc[i][j][r] : -INFINITY);
#pragma unroll
      for (int o = 1; o < 16; o <<= 1) pm = fmaxf(pm, __shfl_xor(pm, o));
      if (rl == 0) rpart[wn * S_LEN + wm * 64 + i * 16 + g * 4 + r] = pm;
    }
  }
#pragma unroll
  for (int j = 0; j < 4; ++j) {
    float cm = -INFINITY;
#pragma unroll
    for (int i = 0; i < 4; ++i)
#pragma unroll
      for (int r = 0; r < 4; ++r)
        cm = fmaxf(cm, ((mrow >> (i * 4 + r)) & 1) ? acc[i][j][r] : -INFINITY);
    cm = fmaxf(cm, __shfl_xor(cm, 16));
    cm = fmaxf(cm, __shfl_xor(cm, 32));
    if (g == 0) cpart[wm * 256 + wn * 64 + j * 16 + rl] = cm;
  }
  __syncthreads();

  // ---- final masked means: wave 0 -> pair b0, wave 1 -> pair b1 ----
  if (w < 2) {
    float v1 = 0.f, c1 = 0.f, v2 = 0.f, c2 = 0.f;
#pragma unroll
    for (int t = 0; t < 2; ++t) {
      const int r = lane + t * 64;
      if (mask1[a * S_LEN + r]) {
        v1 += fmaxf(rpart[(2 * w) * S_LEN + r], rpart[(2 * w + 1) * S_LEN + r]);
        c1 += 1.f;
      }
      const int c = w * 128 + lane + t * 64;
      if (mask2[b0i * S_LEN + c]) {
        v2 += fmaxf(cpart[c], cpart[256 + c]);
        c2 += 1.f;
      }
    }
#pragma unroll
    for (int o = 32; o > 0; o >>= 1) {
      v1 += __shfl_down(v1, o); c1 += __shfl_down(c1, o);
      v2 += __shfl_down(v2, o); c2 += __shfl_down(c2, o);
    }
    if (lane == 0) out[a * 64 + b0i + w] = 0.5f * (v1 / c1 + v2 / c2);
  }
}

extern "C" void kernel_launch(void* const* d_in, const int* in_sizes, int n_in,
                              void* d_out, int out_size, void* d_ws, size_t ws_size,
                              hipStream_t stream) {
  const float* x1 = (const float*)d_in[0];
  const int* mask1 = (const int*)d_in[1];
  const float* x2 = (const float*)d_in[2];
  const int* mask2 = (const int*)d_in[3];
  float* out = (float*)d_out;

  unsigned short* xn1 = (unsigned short*)d_ws;         // 64*128*768 bf16
  unsigned short* xn2 = xn1 + (size_t)64 * 128 * 768;  // 12.6 MB each

  norm_bf16_kernel<<<16384, 256, 0, stream>>>(x1, x2, xn1, xn2);
  rwmd_kernel<<<64 * 32, 512, 0, stream>>>(xn1, xn2, mask1, mask2, out);
}